// Round 3
// baseline (195.613 us; speedup 1.0000x reference)
//
#include <hip/hip_runtime.h>

#define NN 100
#define CC 256
#define NKK 103
#define LDPW 136   // PW stride (bf16): 272 B rows, 16B-aligned frags, 2-way bank alias (free)
#define OTS 260    // out-transpose stride (f32): 1040 B rows, 16B-aligned

typedef __bf16 bf16;
typedef __bf16 bf16x4 __attribute__((ext_vector_type(4)));
typedef __bf16 bf16x8 __attribute__((ext_vector_type(8)));
typedef float f32x4 __attribute__((ext_vector_type(4)));

// kernel0: W (f32 [256][103]) -> Wt (bf16 [103][256]) in workspace.
__global__ void wl_transpose(const float* __restrict__ W, bf16* __restrict__ Wt)
{
    int idx = blockIdx.x * 256 + threadIdx.x;
    if (idx < NKK * CC) {
        int ka = idx >> 8;      // /256
        int k  = idx & 255;
        Wt[ka * CC + k] = (bf16)W[k * NKK + ka];
    }
}

// SMEM layout:
// [    0, 27200)  PW   bf16 [100][136]
// [27200, 28400)  DW   f32  [100][3]
// [28400, 34800)  RP   f32  [8][100][2]
// [52000, 52800)  RS   f32  [100][2]           (outside OT alias range!)
// phase D: OT f32 [50][260] aliases [0, 52000)  (PW/DW/RP dead by then)
//
// Phase A has NO LDS and NO barriers: wave w owns q row-tile w (read once,
// direct from global), Wt (51 KB, block-invariant) streams from L2.
// Register budget: __launch_bounds__(512,4) => 128 unified VGPR+AGPR/wave.
// sched_barrier(0) fences cap the scheduler's load-hoisting windows (the
// round-0/2 spill source: ~44 f32/thread of scratch traffic).
__global__ __launch_bounds__(512, 4)
void dysepconv_fused(const float* __restrict__ query,
                     const float* __restrict__ value,
                     const bf16*  __restrict__ Wt,
                     const float* __restrict__ bwl,
                     const float* __restrict__ gamma,
                     const float* __restrict__ beta,
                     float* __restrict__ out)
{
    __shared__ __align__(16) char SMEM[52800];
    bf16*  PW = (bf16*)SMEM;
    float (*DW)[3]     = (float(*)[3])(SMEM + 27200);
    float (*RP)[NN][2] = (float(*)[NN][2])(SMEM + 28400);
    float (*RS)[2]     = (float(*)[2])(SMEM + 52000);
    float* OT = (float*)SMEM;

    const int t    = threadIdx.x;
    const int w    = t >> 6;          // wave 0..7
    const int lane = t & 63;
    const int ln16 = lane & 15;
    const int g    = lane >> 4;
    const int hi8  = g * 8;
    const int b    = blockIdx.x;
    const int cb   = w * 16 + ln16;   // channel (phase B/D)

    const float* qb = query + (size_t)b * NN * CC;
    const float* vb = value + (size_t)b * NN * CC;

    // ---------------- Phase A: dy = q @ W + bias (no LDS, no barriers) ----------------
    // wave w: dy rows w*16..w*16+15, all 103 cols (7 col-tiles J).
    f32x4 acc1[7];
    #pragma unroll
    for (int J = 0; J < 7; ++J) acc1[J] = (f32x4){0.f, 0.f, 0.f, 0.f};

    if (w < 7) {
        const int qrow = (w * 16 + ln16 < NN) ? (w * 16 + ln16) : (NN - 1); // clamp: D-rows>=100 discarded
        const float* qr = qb + qrow * CC;
        #pragma unroll
        for (int kc = 0; kc < 4; ++kc) {
            bf16x8 qf[2];
            #pragma unroll
            for (int s = 0; s < 2; ++s) {
                f32x4 a0 = *(const f32x4*)(qr + kc * 64 + s * 32 + hi8);
                f32x4 a1 = *(const f32x4*)(qr + kc * 64 + s * 32 + hi8 + 4);
                #pragma unroll
                for (int i = 0; i < 4; ++i) { qf[s][i] = (bf16)a0[i]; qf[s][i + 4] = (bf16)a1[i]; }
            }
            #pragma unroll
            for (int J = 0; J < 7; ++J) {
                const int rB = (J * 16 + ln16 < NKK) ? (J * 16 + ln16) : (NKK - 1); // clamp: cols>=103 discarded
                bf16x8 bv0 = *(const bf16x8*)(Wt + rB * CC + kc * 64 + hi8);
                bf16x8 bv1 = *(const bf16x8*)(Wt + rB * CC + kc * 64 + 32 + hi8);
                acc1[J] = __builtin_amdgcn_mfma_f32_16x16x32_bf16(qf[0], bv0, acc1[J], 0, 0, 0);
                acc1[J] = __builtin_amdgcn_mfma_f32_16x16x32_bf16(qf[1], bv1, acc1[J], 0, 0, 0);
                if (J == 3) __builtin_amdgcn_sched_barrier(0);   // cap hoisted Wt-frag live range
            }
        }
    }

    // epilogue A: zero PW k-pad cols (must be exact 0)
    for (int i = t; i < NN * 28; i += 512) {
        int r = i / 28, m = 100 + (i - (i / 28) * 28);
        PW[r * LDPW + m] = (bf16)0.f;
    }
    // prefetch value loads for ks=0 (latency hides under epilogue + barrier)
    float xv[8], yv[8];
    #pragma unroll
    for (int j = 0; j < 8; ++j) {
        int m = hi8 + j;                       // ks=0: m < 32 < NN always
        const float* vr = vb + m * CC;
        xv[j] = vr[cb];
        yv[j] = vr[cb + 128];
    }
    // epilogue A: write pw (bf16) / dw (fp32).  D: row = w*16+g*4+r, col = J*16+ln16
    if (w < 7) {
        #pragma unroll
        for (int J = 0; J < 7; ++J) {
            int kap = J * 16 + ln16;
            float bw = (kap < NKK) ? bwl[kap] : 0.f;
            #pragma unroll
            for (int r = 0; r < 4; ++r) {
                int n = w * 16 + g * 4 + r;
                if (n < NN && kap < NKK) {
                    float v = acc1[J][r] + bw;
                    if (kap < 3) DW[n][kap] = v;
                    else         PW[n * LDPW + (kap - 3)] = (bf16)v;
                }
            }
        }
    }
    __syncthreads();   // PW/DW visible

    // ---------------- Phase B/C: conv (batched loads, single drain) + GEMM2 ----------------
    f32x4 acc2[2][7];
    #pragma unroll
    for (int st = 0; st < 2; ++st)
        #pragma unroll
        for (int I = 0; I < 7; ++I) acc2[st][I] = (f32x4){0.f, 0.f, 0.f, 0.f};

    #pragma unroll
    for (int ks = 0; ks < 4; ++ks) {
        if (ks) {   // batch all 16 value loads for this ks, one drain
            #pragma unroll
            for (int j = 0; j < 8; ++j) {
                int m = ks * 32 + hi8 + j;
                bool mv = (m < NN);
                const float* vr = vb + m * CC;
                xv[j] = mv ? vr[cb]       : 0.f;
                yv[j] = mv ? vr[cb + 128] : 0.f;
            }
        }
        bf16x8 dv0, dv1;
        #pragma unroll
        for (int j = 0; j < 8; ++j) {
            int  m  = ks * 32 + hi8 + j;
            bool mv = (m < NN);
            int  mc = mv ? m : (NN - 1);
            float w0 = DW[mc][0], w1 = DW[mc][1], w2 = DW[mc][2];
            float x0 = xv[j], y0 = yv[j];
            float xm = __shfl(x0, (lane - 1) & 63), xp = __shfl(x0, (lane + 1) & 63);
            float ym = __shfl(y0, (lane - 1) & 63), yp = __shfl(y0, (lane + 1) & 63);
            if (ln16 == 0) {
                xm = (mv && cb > 0) ? vb[m * CC + cb - 1] : 0.f;
                ym = mv ? vb[m * CC + cb + 127] : 0.f;
            }
            if (ln16 == 15) {
                xp = mv ? vb[m * CC + cb + 1] : 0.f;
                yp = (mv && cb + 129 < CC) ? vb[m * CC + cb + 129] : 0.f;
            }
            float d0 = w0 * xm + w1 * x0 + w2 * xp;
            float d1 = w0 * ym + w1 * y0 + w2 * yp;
            dv0[j] = (bf16)(mv ? fmaxf(d0, 0.f) : 0.f);
            dv1[j] = (bf16)(mv ? fmaxf(d1, 0.f) : 0.f);
            if (j == 3) __builtin_amdgcn_sched_barrier(0);   // cap hoisted boundary-load live range
        }
        #pragma unroll
        for (int I = 0; I < 7; ++I) {
            int row = I * 16 + ln16;
            row = (row < NN) ? row : (NN - 1);   // PW has 100 rows; clamped rows discarded
            bf16x8 af = *(const bf16x8*)&PW[row * LDPW + ks * 32 + hi8];
            acc2[0][I] = __builtin_amdgcn_mfma_f32_16x16x32_bf16(af, dv0, acc2[0][I], 0, 0, 0);
            acc2[1][I] = __builtin_amdgcn_mfma_f32_16x16x32_bf16(af, dv1, acc2[1][I], 0, 0, 0);
            if (I == 3) __builtin_amdgcn_sched_barrier(0);   // cap hoisted PW-frag live range
        }
    }

    // LN affine params (L2-hot)
    const float gm0 = gamma[cb], gm1 = gamma[cb + 128];
    const float bt0 = beta[cb],  bt1 = beta[cb + 128];

    // ---------------- Phase D: LayerNorm ----------------
    #pragma unroll
    for (int I = 0; I < 7; ++I) {
        #pragma unroll
        for (int r = 0; r < 4; ++r) {
            float a = acc2[0][I][r], e = acc2[1][I][r];
            float s1 = a + e, s2 = a * a + e * e;
            #pragma unroll
            for (int mk = 1; mk < 16; mk <<= 1) {
                s1 += __shfl_xor(s1, mk);
                s2 += __shfl_xor(s2, mk);
            }
            int n = I * 16 + g * 4 + r;
            if (ln16 == 0 && n < NN) {
                RP[w][n][0] = s1;
                RP[w][n][1] = s2;
            }
        }
    }
    __syncthreads();   // also: all PW reads (GEMM2) complete -> OT may alias PW/DW/RP after next barrier
    if (t < NN) {
        float S1 = 0.f, S2 = 0.f;
        #pragma unroll
        for (int wi = 0; wi < 8; ++wi) { S1 += RP[wi][t][0]; S2 += RP[wi][t][1]; }
        float mu  = S1 * (1.f / 256.f);
        float var = S2 * (1.f / 256.f) - mu * mu;
        RS[t][0] = mu;
        RS[t][1] = rsqrtf(fmaxf(var, 0.f) + 1e-5f);
    }
    __syncthreads();   // RS visible; RP dead

    // normalize + transpose through LDS in 2 chunks of 50 rows
    float* ob = out + (size_t)b * NN * CC;
    #pragma unroll
    for (int h = 0; h < 2; ++h) {
        const int n0 = h * 50;
        #pragma unroll
        for (int I = 0; I < 7; ++I) {
            #pragma unroll
            for (int r = 0; r < 4; ++r) {
                int n = I * 16 + g * 4 + r;
                if (n >= n0 && n < n0 + 50 && n < NN) {
                    float mu = RS[n][0], rs = RS[n][1];
                    int rt = n - n0;
                    OT[rt * OTS + cb]       = (acc2[0][I][r] - mu) * rs * gm0 + bt0;
                    OT[rt * OTS + cb + 128] = (acc2[1][I][r] - mu) * rs * gm1 + bt1;
                }
            }
        }
        __syncthreads();
        #pragma unroll
        for (int p = 0; p < 7; ++p) {
            int idx = p * 512 + t;              // 50 rows x 64 f32x4 = 3200
            if (idx < 50 * 64) {
                int row = idx >> 6, c4 = (idx & 63) << 2;
                *(f32x4*)(ob + (size_t)(n0 + row) * CC + c4) = *(const f32x4*)&OT[row * OTS + c4];
            }
        }
        if (h == 0) __syncthreads();
    }
}

extern "C" void kernel_launch(void* const* d_in, const int* in_sizes, int n_in,
                              void* d_out, int out_size, void* d_ws, size_t ws_size,
                              hipStream_t stream) {
    const float* query = (const float*)d_in[0];
    const float* value = (const float*)d_in[1];
    const float* W     = (const float*)d_in[2];
    const float* bwl   = (const float*)d_in[3];
    const float* gamma = (const float*)d_in[4];
    const float* beta  = (const float*)d_in[5];
    bf16* Wt = (bf16*)d_ws;   // 103*256*2 = 52736 B

    wl_transpose<<<dim3((NKK * CC + 255) / 256), dim3(256), 0, stream>>>(W, Wt);
    dysepconv_fused<<<dim3(512), dim3(512), 0, stream>>>(query, value, Wt, bwl, gamma, beta, (float*)d_out);
}

// Round 4
// 184.482 us; speedup vs baseline: 1.0603x; 1.0603x over previous
//
#include <hip/hip_runtime.h>

#define NN 100
#define CC 256
#define NKK 103
#define LDPW 136   // PW stride (bf16): 272 B rows, 16B-aligned frags, 2-way bank alias (free)
#define OTS 260    // out-transpose stride (f32): 1040 B rows, 16B-aligned

typedef __bf16 bf16;
typedef __bf16 bf16x8 __attribute__((ext_vector_type(8)));
typedef float f32x4 __attribute__((ext_vector_type(4)));

// kernel0: W (f32 [256][103]) -> Wt (bf16 [103][256]) in workspace.
__global__ void wl_transpose(const float* __restrict__ W, bf16* __restrict__ Wt)
{
    int idx = blockIdx.x * 256 + threadIdx.x;
    if (idx < NKK * CC) {
        int ka = idx >> 8;      // /256
        int k  = idx & 255;
        Wt[ka * CC + k] = (bf16)W[k * NKK + ka];
    }
}

// 256-thread / 4-wave blocks, one batch each, 512 blocks.
// __launch_bounds__(256,2) => 256 unified VGPR+AGPR per wave: the full phase-B/C
// working set (acc2 112 AGPR + ~100 arch VGPR) fits with NO scratch spills --
// rounds 0-3 all carried ~40 MB of spill traffic at the 128-reg operating point
// and were latency-bound on scratch reloads (dur flat at ~86 us through three
// structural rewrites).  2 blocks/CU (reg-bound), all 512 blocks co-resident.
//
// SMEM layout:
// [    0, 27200)  PW   bf16 [100][136]
// [27200, 28400)  DW   f32  [100][3]
// [28400, 31600)  RP   f32  [4][100][2]
// [52000, 52800)  RS   f32  [100][2]           (outside OT alias range)
// phase D: OT f32 [50][260] aliases [0, 52000)  (PW/DW/RP dead by then)
__global__ __launch_bounds__(256, 2)
void dysepconv_fused(const float* __restrict__ query,
                     const float* __restrict__ value,
                     const bf16*  __restrict__ Wt,
                     const float* __restrict__ bwl,
                     const float* __restrict__ gamma,
                     const float* __restrict__ beta,
                     float* __restrict__ out)
{
    __shared__ __align__(16) char SMEM[52800];
    bf16*  PW = (bf16*)SMEM;
    float (*DW)[3]     = (float(*)[3])(SMEM + 27200);
    float (*RP)[NN][2] = (float(*)[NN][2])(SMEM + 28400);
    float (*RS)[2]     = (float(*)[2])(SMEM + 52000);
    float* OT = (float*)SMEM;

    const int t    = threadIdx.x;
    const int w    = t >> 6;          // wave 0..3
    const int lane = t & 63;
    const int ln16 = lane & 15;
    const int g    = lane >> 4;
    const int hi8  = g * 8;
    const int b    = blockIdx.x;
    const int cb0  = w * 16 + ln16;   // channel base 0..63; lane owns cb0 + 64*s, s=0..3

    const float* qb = query + (size_t)b * NN * CC;
    const float* vb = value + (size_t)b * NN * CC;

    // ---------------- Phase A: dy = q @ W + bias (no LDS, no barriers) ----------------
    // wave w owns dy row-tiles {w, w+4} (tile 7 doesn't exist: wave 3 skips u=1).
    f32x4 acc1[2][7];
    #pragma unroll
    for (int u = 0; u < 2; ++u)
        #pragma unroll
        for (int J = 0; J < 7; ++J) acc1[u][J] = (f32x4){0.f, 0.f, 0.f, 0.f};

    #pragma unroll
    for (int u = 0; u < 2; ++u) {
        if (u == 0 || w < 3) {                 // wave-uniform
            const int tile = w + u * 4;        // 0..6
            const int qrow = (tile * 16 + ln16 < NN) ? (tile * 16 + ln16) : (NN - 1); // clamp: D-rows>=100 discarded
            const float* qr = qb + qrow * CC;
            #pragma unroll
            for (int kc = 0; kc < 4; ++kc) {
                bf16x8 qf[2];
                #pragma unroll
                for (int s = 0; s < 2; ++s) {
                    f32x4 a0 = *(const f32x4*)(qr + kc * 64 + s * 32 + hi8);
                    f32x4 a1 = *(const f32x4*)(qr + kc * 64 + s * 32 + hi8 + 4);
                    #pragma unroll
                    for (int i = 0; i < 4; ++i) { qf[s][i] = (bf16)a0[i]; qf[s][i + 4] = (bf16)a1[i]; }
                }
                #pragma unroll
                for (int J = 0; J < 7; ++J) {
                    const int rB = (J * 16 + ln16 < NKK) ? (J * 16 + ln16) : (NKK - 1); // clamp: cols>=103 discarded
                    bf16x8 bv0 = *(const bf16x8*)(Wt + rB * CC + kc * 64 + hi8);
                    bf16x8 bv1 = *(const bf16x8*)(Wt + rB * CC + kc * 64 + 32 + hi8);
                    acc1[u][J] = __builtin_amdgcn_mfma_f32_16x16x32_bf16(qf[0], bv0, acc1[u][J], 0, 0, 0);
                    acc1[u][J] = __builtin_amdgcn_mfma_f32_16x16x32_bf16(qf[1], bv1, acc1[u][J], 0, 0, 0);
                }
            }
        }
    }

    // epilogue A: zero PW k-pad cols (must be exact 0)
    for (int i = t; i < NN * 28; i += 256) {
        int r = i / 28, m = 100 + (i - (i / 28) * 28);
        PW[r * LDPW + m] = (bf16)0.f;
    }
    // prefetch value loads for ks=0 (latency hides under epilogue + barrier)
    float xv[4][8];
    #pragma unroll
    for (int s = 0; s < 4; ++s)
        #pragma unroll
        for (int j = 0; j < 8; ++j) {
            int m = hi8 + j;                   // ks=0: m < 32 < NN always
            xv[s][j] = vb[m * CC + cb0 + 64 * s];
        }
    // epilogue A: write pw (bf16) / dw (fp32).  D: row = tile*16+g*4+r, col = J*16+ln16
    #pragma unroll
    for (int u = 0; u < 2; ++u) {
        if (u == 0 || w < 3) {
            #pragma unroll
            for (int J = 0; J < 7; ++J) {
                int kap = J * 16 + ln16;
                float bw = (kap < NKK) ? bwl[kap] : 0.f;
                #pragma unroll
                for (int r = 0; r < 4; ++r) {
                    int n = (w + u * 4) * 16 + g * 4 + r;
                    if (n < NN && kap < NKK) {
                        float v = acc1[u][J][r] + bw;
                        if (kap < 3) DW[n][kap] = v;
                        else         PW[n * LDPW + (kap - 3)] = (bf16)v;
                    }
                }
            }
        }
    }
    __syncthreads();   // PW/DW visible

    // ---------------- Phase B/C: conv (4 channel segments/lane) + GEMM2 ----------------
    f32x4 acc2[4][7];
    #pragma unroll
    for (int s = 0; s < 4; ++s)
        #pragma unroll
        for (int I = 0; I < 7; ++I) acc2[s][I] = (f32x4){0.f, 0.f, 0.f, 0.f};

    #pragma unroll
    for (int ks = 0; ks < 4; ++ks) {
        if (ks) {   // batch all 32 value loads for this ks; free regs let compiler hoist
            #pragma unroll
            for (int s = 0; s < 4; ++s)
                #pragma unroll
                for (int j = 0; j < 8; ++j) {
                    int m = ks * 32 + hi8 + j;
                    bool mv = (m < NN);
                    xv[s][j] = mv ? vb[m * CC + cb0 + 64 * s] : 0.f;
                }
        }
        bf16x8 dv[4];
        #pragma unroll
        for (int j = 0; j < 8; ++j) {
            int  m  = ks * 32 + hi8 + j;
            bool mv = (m < NN);
            int  mc = mv ? m : (NN - 1);
            float w0 = DW[mc][0], w1 = DW[mc][1], w2 = DW[mc][2];   // row-only: shared by 4 segs
            #pragma unroll
            for (int s = 0; s < 4; ++s) {
                int c = cb0 + 64 * s;
                float x0 = xv[s][j];
                float xm = __shfl(x0, (lane - 1) & 63);
                float xp = __shfl(x0, (lane + 1) & 63);
                if (ln16 == 0)  xm = (mv && c > 0)      ? vb[m * CC + c - 1] : 0.f;
                if (ln16 == 15) xp = (mv && c + 1 < CC) ? vb[m * CC + c + 1] : 0.f;
                float d = w0 * xm + w1 * x0 + w2 * xp;
                dv[s][j] = (bf16)(mv ? fmaxf(d, 0.f) : 0.f);
            }
        }
        #pragma unroll
        for (int I = 0; I < 7; ++I) {
            int row = I * 16 + ln16;
            row = (row < NN) ? row : (NN - 1);   // PW has 100 rows; clamped rows discarded
            bf16x8 af = *(const bf16x8*)&PW[row * LDPW + ks * 32 + hi8];   // 1 read feeds 4 MFMAs
            #pragma unroll
            for (int s = 0; s < 4; ++s)
                acc2[s][I] = __builtin_amdgcn_mfma_f32_16x16x32_bf16(af, dv[s], acc2[s][I], 0, 0, 0);
        }
    }

    // LN affine params (L2-hot)
    float gm[4], bt[4];
    #pragma unroll
    for (int s = 0; s < 4; ++s) { gm[s] = gamma[cb0 + 64 * s]; bt[s] = beta[cb0 + 64 * s]; }

    // ---------------- Phase D: LayerNorm ----------------
    #pragma unroll
    for (int I = 0; I < 7; ++I) {
        #pragma unroll
        for (int r = 0; r < 4; ++r) {
            float s1 = 0.f, s2 = 0.f;
            #pragma unroll
            for (int s = 0; s < 4; ++s) {
                float a = acc2[s][I][r];
                s1 += a; s2 += a * a;
            }
            #pragma unroll
            for (int mk = 1; mk < 16; mk <<= 1) {
                s1 += __shfl_xor(s1, mk);
                s2 += __shfl_xor(s2, mk);
            }
            int n = I * 16 + g * 4 + r;
            if (ln16 == 0 && n < NN) {
                RP[w][n][0] = s1;
                RP[w][n][1] = s2;
            }
        }
    }
    __syncthreads();   // RP visible; also all PW/DW reads complete -> OT may alias later
    if (t < NN) {
        float S1 = 0.f, S2 = 0.f;
        #pragma unroll
        for (int wi = 0; wi < 4; ++wi) { S1 += RP[wi][t][0]; S2 += RP[wi][t][1]; }
        float mu  = S1 * (1.f / 256.f);
        float var = S2 * (1.f / 256.f) - mu * mu;
        RS[t][0] = mu;
        RS[t][1] = rsqrtf(fmaxf(var, 0.f) + 1e-5f);
    }
    __syncthreads();   // RS visible; RP dead -> OT alias safe

    // normalize + transpose through LDS in 2 chunks of 50 rows
    float* ob = out + (size_t)b * NN * CC;
    #pragma unroll
    for (int h = 0; h < 2; ++h) {
        const int n0 = h * 50;
        #pragma unroll
        for (int I = 0; I < 7; ++I) {
            #pragma unroll
            for (int r = 0; r < 4; ++r) {
                int n = I * 16 + g * 4 + r;
                if (n >= n0 && n < n0 + 50 && n < NN) {
                    float mu = RS[n][0], rs = RS[n][1];
                    int rt = n - n0;
                    #pragma unroll
                    for (int s = 0; s < 4; ++s)
                        OT[rt * OTS + cb0 + 64 * s] = (acc2[s][I][r] - mu) * rs * gm[s] + bt[s];
                }
            }
        }
        __syncthreads();
        #pragma unroll
        for (int p = 0; p < 13; ++p) {
            int idx = p * 256 + t;              // 50 rows x 64 f32x4 = 3200
            if (idx < 50 * 64) {
                int row = idx >> 6, c4 = (idx & 63) << 2;
                *(f32x4*)(ob + (size_t)(n0 + row) * CC + c4) = *(const f32x4*)&OT[row * OTS + c4];
            }
        }
        if (h == 0) __syncthreads();
    }
}

extern "C" void kernel_launch(void* const* d_in, const int* in_sizes, int n_in,
                              void* d_out, int out_size, void* d_ws, size_t ws_size,
                              hipStream_t stream) {
    const float* query = (const float*)d_in[0];
    const float* value = (const float*)d_in[1];
    const float* W     = (const float*)d_in[2];
    const float* bwl   = (const float*)d_in[3];
    const float* gamma = (const float*)d_in[4];
    const float* beta  = (const float*)d_in[5];
    bf16* Wt = (bf16*)d_ws;   // 103*256*2 = 52736 B

    wl_transpose<<<dim3((NKK * CC + 255) / 256), dim3(256), 0, stream>>>(W, Wt);
    dysepconv_fused<<<dim3(512), dim3(256), 0, stream>>>(query, value, Wt, bwl, gamma, beta, (float*)d_out);
}